// Round 4
// baseline (685.968 us; speedup 1.0000x reference)
//
#include <hip/hip_runtime.h>
#include <hip/hip_fp16.h>

// Problem constants (fixed by the reference)
constexpr int NN = 100000;          // nodes
constexpr int EE = 1600000;         // edges (without self loops)
constexpr int ET = EE + NN;         // edges + self loops
constexpr float NEG = 0.2f;

typedef _Float16 f16x8 __attribute__((ext_vector_type(8)));
typedef _Float16 f16x4 __attribute__((ext_vector_type(4)));
typedef float    f32x4 __attribute__((ext_vector_type(4)));

// ---------------------------------------------------------------------------
// CSR build: histogram -> scan -> scatter (records dst per slot too)
// ---------------------------------------------------------------------------
__global__ __launch_bounds__(256) void k_count(const int* __restrict__ ei, int* __restrict__ deg) {
    int i = blockIdx.x * 256 + threadIdx.x;
    if (i >= ET) return;
    int dst = (i < EE) ? ei[EE + i] : (i - EE);
    atomicAdd(&deg[dst], 1);
}

__global__ __launch_bounds__(256) void k_part(const int* __restrict__ deg, int* __restrict__ part) {
    __shared__ int sh[256];
    int i = blockIdx.x * 256 + threadIdx.x;
    sh[threadIdx.x] = (i < NN) ? deg[i] : 0;
    __syncthreads();
    for (int o = 128; o; o >>= 1) {
        if (threadIdx.x < o) sh[threadIdx.x] += sh[threadIdx.x + o];
        __syncthreads();
    }
    if (threadIdx.x == 0) part[blockIdx.x] = sh[0];
}

__global__ __launch_bounds__(512) void k_scanp(int* __restrict__ part, int nb) {
    __shared__ int sh[512];
    int t = threadIdx.x;
    int v = (t < nb) ? part[t] : 0;
    sh[t] = v;
    __syncthreads();
    for (int o = 1; o < 512; o <<= 1) {
        int u = (t >= o) ? sh[t - o] : 0;
        __syncthreads();
        sh[t] += u;
        __syncthreads();
    }
    if (t < nb) part[t] = sh[t] - v;   // exclusive
}

__global__ __launch_bounds__(256) void k_scan(const int* __restrict__ deg, const int* __restrict__ part,
                                              int* __restrict__ rs, int* __restrict__ cur) {
    __shared__ int sh[256];
    int t = threadIdx.x;
    int i = blockIdx.x * 256 + t;
    int v = (i < NN) ? deg[i] : 0;
    sh[t] = v;
    __syncthreads();
    for (int o = 1; o < 256; o <<= 1) {
        int u = (t >= o) ? sh[t - o] : 0;
        __syncthreads();
        sh[t] += u;
        __syncthreads();
    }
    int incl = sh[t];
    int base = part[blockIdx.x];
    if (i < NN) {
        rs[i]  = base + incl - v;
        cur[i] = base + incl - v;
        if (i == NN - 1) rs[NN] = base + incl;
    }
}

__global__ __launch_bounds__(256) void k_scatter(const int* __restrict__ ei, int* __restrict__ cur,
                                                 int* __restrict__ csr, int* __restrict__ dstv) {
    int i = blockIdx.x * 256 + threadIdx.x;
    if (i >= ET) return;
    int src, dst;
    if (i < EE) { src = ei[i]; dst = ei[EE + i]; }
    else        { src = i - EE; dst = i - EE; }
    int pos = atomicAdd(&cur[dst], 1);
    csr[pos]  = src;
    dstv[pos] = dst;
}

// ---------------------------------------------------------------------------
// MFMA GEMM: xp = x @ W (fp16 inputs to matrix core, fp32 accumulate).
// OUT_MODE 1: plain fp16 row of C halves.
// ---------------------------------------------------------------------------
template <int K, int C, int OUT_MODE, bool SRCF32>
__global__ __launch_bounds__(256) void gemm_mfma(const void* __restrict__ xv, const float* __restrict__ W,
                                                 __half* __restrict__ xp, int n, int set_off) {
    constexpr int KC  = 64;          // K-chunk per stage
    constexpr int AST = KC + 8;      // padded LDS stride (halves)
    constexpr int NT  = C / 16;      // 16-col tiles
    constexpr int NST = K / KC;      // stages
    __shared__ _Float16 a_lds[128 * AST];
    __shared__ _Float16 w_lds[C * AST];

    const int tid  = threadIdx.x;
    const int w    = tid >> 6;
    const int lane = tid & 63;
    const int quad = lane >> 4;
    const int l16  = lane & 15;
    const long r0  = (long)blockIdx.x * 128;

    f32x4 acc[2][NT];
#pragma unroll
    for (int s = 0; s < 2; s++)
#pragma unroll
        for (int t = 0; t < NT; t++) acc[s][t] = (f32x4){0.f, 0.f, 0.f, 0.f};

    for (int st = 0; st < NST; ++st) {
        const int k0 = st * KC;
        // stage A: 128 rows x KC halves (convert fp32->fp16 if needed)
        for (int i = tid; i < 128 * (KC / 4); i += 256) {
            int r = i / (KC / 4);
            int q = i % (KC / 4);
            long row = r0 + r;
            f16x4 hv = (f16x4){0, 0, 0, 0};
            if (row < n) {
                if (SRCF32) {
                    float4 v = ((const float4*)xv)[row * (K / 4) + (k0 / 4) + q];
                    hv = (f16x4){(_Float16)v.x, (_Float16)v.y, (_Float16)v.z, (_Float16)v.w};
                } else {
                    hv = ((const f16x4*)xv)[row * (K / 4) + (k0 / 4) + q];
                }
            }
            *(f16x4*)&a_lds[r * AST + q * 4] = hv;
        }
        // stage W^T: w_lds[n][k] from W[k][n] (coalesced global reads over n)
        for (int i = tid; i < C * (KC / 4); i += 256) {
            int nn = i / (KC / 4);
            int kq = i % (KC / 4);
            f16x4 hv;
            hv.x = (_Float16)W[(long)(k0 + kq * 4 + 0) * C + nn];
            hv.y = (_Float16)W[(long)(k0 + kq * 4 + 1) * C + nn];
            hv.z = (_Float16)W[(long)(k0 + kq * 4 + 2) * C + nn];
            hv.w = (_Float16)W[(long)(k0 + kq * 4 + 3) * C + nn];
            *(f16x4*)&w_lds[nn * AST + kq * 4] = hv;
        }
        __syncthreads();

#pragma unroll
        for (int ks = 0; ks < KC; ks += 32) {
            f16x8 a0 = *(const f16x8*)&a_lds[(w * 32 + l16) * AST + ks + quad * 8];
            f16x8 a1 = *(const f16x8*)&a_lds[(w * 32 + 16 + l16) * AST + ks + quad * 8];
#pragma unroll
            for (int t = 0; t < NT; t++) {
                f16x8 b = *(const f16x8*)&w_lds[(t * 16 + l16) * AST + ks + quad * 8];
                acc[0][t] = __builtin_amdgcn_mfma_f32_16x16x32_f16(a0, b, acc[0][t], 0, 0, 0);
                acc[1][t] = __builtin_amdgcn_mfma_f32_16x16x32_f16(a1, b, acc[1][t], 0, 0, 0);
            }
        }
        __syncthreads();
    }

    // epilogue: C/D layout col=l16, row=quad*4+reg
#pragma unroll
    for (int sub = 0; sub < 2; sub++) {
        long rb = r0 + w * 32 + sub * 16 + quad * 4;
#pragma unroll
        for (int t = 0; t < NT; t++) {
            int c = t * 16 + l16;
#pragma unroll
            for (int rg = 0; rg < 4; rg++) {
                long row = rb + rg;
                if (row < n) {
                    __half hv = __float2half(acc[sub][t][rg]);
                    if (OUT_MODE == 0)
                        xp[row * 256 + ((c >> 1) << 2) + (c & 1) + set_off] = hv;
                    else
                        xp[row * (long)C + c] = hv;
                }
            }
        }
    }
}

// ---------------------------------------------------------------------------
// Attention coefficients for conv1 from the two plain fp16 feature arrays.
// Thread per (v, head). att_sp[v*4+h] = <xp_p[v], as1[h]>, etc.
// ---------------------------------------------------------------------------
__global__ __launch_bounds__(256) void attn1_plain(const __half2* __restrict__ xp_p,
                                                   const __half2* __restrict__ xp_g,
                                                   const float* __restrict__ as_w, const float* __restrict__ ad_w,
                                                   float* __restrict__ att_sp, float* __restrict__ att_dp,
                                                   float* __restrict__ att_sg, float* __restrict__ att_dg, int n) {
    int idx = blockIdx.x * 256 + threadIdx.x;
    if (idx >= n * 4) return;
    int v = idx >> 2, hh = idx & 3;
    const __half2* rp = xp_p + (long)v * 64 + hh * 16;
    const __half2* rg = xp_g + (long)v * 64 + hh * 16;
    const float* a1 = as_w + hh * 32;
    const float* a2 = ad_w + hh * 32;
    float sp1 = 0.f, sp2 = 0.f, sg1 = 0.f, sg2 = 0.f;
#pragma unroll
    for (int t = 0; t < 16; t++) {
        float2 fp = __half22float2(rp[t]);
        float2 fg = __half22float2(rg[t]);
        float2 w1 = *(const float2*)(a1 + 2 * t);
        float2 w2 = *(const float2*)(a2 + 2 * t);
        sp1 += fp.x * w1.x + fp.y * w1.y;
        sp2 += fp.x * w2.x + fp.y * w2.y;
        sg1 += fg.x * w1.x + fg.y * w1.y;
        sg2 += fg.x * w2.x + fg.y * w2.y;
    }
    att_sp[idx] = sp1; att_dp[idx] = sp2;
    att_sg[idx] = sg1; att_dg[idx] = sg2;
}

// attention for conv2 (H=1, C=64), fp16 xp
__global__ __launch_bounds__(256) void attn2_kernel(const __half2* __restrict__ xp,
                                                    const float* __restrict__ as_w, const float* __restrict__ ad_w,
                                                    float* __restrict__ asrc, float* __restrict__ adst, int n) {
    int v = blockIdx.x * 256 + threadIdx.x;
    if (v >= n) return;
    const __half2* p = xp + (long)v * 32;
    float s1 = 0.f, s2 = 0.f;
#pragma unroll
    for (int c = 0; c < 32; c++) {
        float2 xv = __half22float2(p[c]);
        float2 w1 = *(const float2*)(as_w + 2 * c);
        float2 w2 = *(const float2*)(ad_w + 2 * c);
        s1 += xv.x * w1.x + xv.y * w1.y;
        s2 += xv.x * w2.x + xv.y * w2.y;
    }
    asrc[v] = s1;
    adst[v] = s2;
}

// ---------------------------------------------------------------------------
// Per-edge exp-weights for conv1, both sets: wb_p[j][4], wb_g[j][4]
// (16B/edge per set, streamed sequentially by the conv passes).
// ---------------------------------------------------------------------------
__global__ __launch_bounds__(256) void w1prep2(const int* __restrict__ csr, const int* __restrict__ dstv,
                                               const float4* __restrict__ att_sp4, const float4* __restrict__ att_dp4,
                                               const float4* __restrict__ att_sg4, const float4* __restrict__ att_dg4,
                                               float4* __restrict__ wbp4, float4* __restrict__ wbg4) {
    int j = blockIdx.x * 256 + threadIdx.x;
    if (j >= ET) return;
    int s = csr[j], v = dstv[j];
    float4 sp = att_sp4[s], dp = att_dp4[v];
    float4 sg = att_sg4[s], dg = att_dg4[v];
    auto w = [](float e) { e = (e > 0.f) ? e : NEG * e; return __expf(e); };
    float4 wp, wg;
    wp.x = w(sp.x + dp.x); wp.y = w(sp.y + dp.y);
    wp.z = w(sp.z + dp.z); wp.w = w(sp.w + dp.w);
    wg.x = w(sg.x + dg.x); wg.y = w(sg.y + dg.y);
    wg.z = w(sg.z + dg.z); wg.w = w(sg.w + dg.w);
    wbp4[j] = wp;
    wbg4[j] = wg;
}

// ---------------------------------------------------------------------------
// conv1 single-set pass (v5). Working-set split: this pass reads ONE 25.6MB
// feature array (256B rows) so L2 re-reference distance halves vs the packed
// 51MB layout -> higher hit rate -> fewer counted bytes (the proven wall is
// bytes/3.85TB/s). One wave per dst node; quarter-wave qw handles edges
// j+4k+qw; lane m (0..15) gathers 16B = channels 8m..8m+7. Weights streamed
// (4B/lane/edge from wb). 16-edge full chunks (4 gathers in flight), 4-edge
// clamped tail. Combine via shfl_xor(16,32); qw==0 lanes write uint4 of 8
// fp16 (bias+ReLU applied) into hbuf[v*256 + off + 8m].
// ---------------------------------------------------------------------------
__global__ __launch_bounds__(256) void conv1_pass(const int* __restrict__ rs, const int* __restrict__ csr,
                                                  const uint4* __restrict__ xp,
                                                  const float* __restrict__ wb,
                                                  const float* __restrict__ bias,
                                                  __half* __restrict__ out, int off) {
    int v = blockIdx.x * 4 + (threadIdx.x >> 6);
    if (v >= NN) return;
    int lane = threadIdx.x & 63;
    int qw = lane >> 4;                // quarter-wave: edge offset
    int m = lane & 15;                 // channels 8m..8m+7
    int hd = m >> 2;                   // head index for this lane's channels
    int e0 = rs[v], e1 = rs[v + 1];

    float a[8];
#pragma unroll
    for (int i = 0; i < 8; i++) a[i] = 0.f;
    float d = 0.f;

    int j = e0;
    // full chunks: 16 edges, 4 gathers in flight, no predication
    for (; j + 16 <= e1; j += 16) {
        int s[4]; float w[4]; uint4 r[4];
#pragma unroll
        for (int k = 0; k < 4; k++) s[k] = csr[j + 4 * k + qw];
#pragma unroll
        for (int k = 0; k < 4; k++) w[k] = wb[(j + 4 * k + qw) * 4 + hd];
#pragma unroll
        for (int k = 0; k < 4; k++) r[k] = xp[(long)s[k] * 16 + m];
#pragma unroll
        for (int k = 0; k < 4; k++) {
            d += w[k];
            float2 f0 = __half22float2(*(__half2*)&r[k].x);
            float2 f1 = __half22float2(*(__half2*)&r[k].y);
            float2 f2 = __half22float2(*(__half2*)&r[k].z);
            float2 f3 = __half22float2(*(__half2*)&r[k].w);
            a[0] += w[k] * f0.x; a[1] += w[k] * f0.y;
            a[2] += w[k] * f1.x; a[3] += w[k] * f1.y;
            a[4] += w[k] * f2.x; a[5] += w[k] * f2.y;
            a[6] += w[k] * f3.x; a[7] += w[k] * f3.y;
        }
    }
    // tail: 4 edges per iteration, clamped duplicate gathers with zero weight
    for (; j < e1; j += 4) {
        int jj = j + qw;
        int jc = (jj < e1) ? jj : (e1 - 1);
        int s = csr[jc];
        float w = (jj < e1) ? wb[jc * 4 + hd] : 0.f;
        uint4 r = xp[(long)s * 16 + m];
        d += w;
        float2 f0 = __half22float2(*(__half2*)&r.x);
        float2 f1 = __half22float2(*(__half2*)&r.y);
        float2 f2 = __half22float2(*(__half2*)&r.z);
        float2 f3 = __half22float2(*(__half2*)&r.w);
        a[0] += w * f0.x; a[1] += w * f0.y;
        a[2] += w * f1.x; a[3] += w * f1.y;
        a[4] += w * f2.x; a[5] += w * f2.y;
        a[6] += w * f3.x; a[7] += w * f3.y;
    }

    // combine the four quarters (disjoint edge subsets)
#pragma unroll
    for (int i = 0; i < 8; i++) {
        a[i] += __shfl_xor(a[i], 16);
        a[i] += __shfl_xor(a[i], 32);
    }
    d += __shfl_xor(d, 16);
    d += __shfl_xor(d, 32);

    if (qw == 0) {
        float inv = 1.0f / d;
        const float4* b4 = (const float4*)bias;
        float4 bA = b4[2 * m], bB = b4[2 * m + 1];
        __half2 o01 = __floats2half2_rn(fmaxf(a[0] * inv + bA.x, 0.f), fmaxf(a[1] * inv + bA.y, 0.f));
        __half2 o23 = __floats2half2_rn(fmaxf(a[2] * inv + bA.z, 0.f), fmaxf(a[3] * inv + bA.w, 0.f));
        __half2 o45 = __floats2half2_rn(fmaxf(a[4] * inv + bB.x, 0.f), fmaxf(a[5] * inv + bB.y, 0.f));
        __half2 o67 = __floats2half2_rn(fmaxf(a[6] * inv + bB.z, 0.f), fmaxf(a[7] * inv + bB.w, 0.f));
        uint4 st;
        st.x = *(unsigned int*)&o01;
        st.y = *(unsigned int*)&o23;
        st.z = *(unsigned int*)&o45;
        st.w = *(unsigned int*)&o67;
        *(uint4*)(out + (long)v * 256 + off + 8 * m) = st;
    }
}

// ---------------------------------------------------------------------------
// Single-pass conv2 edge kernel (H=1, C=64, fp16 xp). Weight inline from
// asrc[s] (400KB) + adst[v] register. Quarter-waves; 16-edge full chunks.
// ---------------------------------------------------------------------------
__global__ __launch_bounds__(256) void conv2_edge(const int* __restrict__ rs, const int* __restrict__ csr,
                                                  const __half* __restrict__ xp,
                                                  const float* __restrict__ asrc,
                                                  const float* __restrict__ adst,
                                                  const float* __restrict__ bias,
                                                  float* __restrict__ out) {
    int v = blockIdx.x * 4 + (threadIdx.x >> 6);
    if (v >= NN) return;
    int lane = threadIdx.x & 63;
    int qw = lane >> 4;                // quarter-wave: edge offset
    int m = lane & 15;                 // channels 4m..4m+3
    int e0 = rs[v], e1 = rs[v + 1];
    const uint2* xp2 = (const uint2*)xp;

    float adv = adst[v];
    auto lrexp = [](float e) { e = (e > 0.f) ? e : NEG * e; return __expf(e); };

    float a0 = 0.f, a1 = 0.f, a2 = 0.f, a3 = 0.f, d = 0.f;

    int j = e0;
    // full chunks: 16 edges, 4 gathers in flight, no predication
    for (; j + 16 <= e1; j += 16) {
        int s[4]; float av[4]; uint2 r[4];
#pragma unroll
        for (int k = 0; k < 4; k++) s[k] = csr[j + 4 * k + qw];
#pragma unroll
        for (int k = 0; k < 4; k++) av[k] = asrc[s[k]];
#pragma unroll
        for (int k = 0; k < 4; k++) r[k] = xp2[(long)s[k] * 16 + m];
#pragma unroll
        for (int k = 0; k < 4; k++) {
            float w = lrexp(av[k] + adv);
            d += w;
            float2 x01 = __half22float2(*(__half2*)&r[k].x);
            float2 x23 = __half22float2(*(__half2*)&r[k].y);
            a0 += w * x01.x; a1 += w * x01.y;
            a2 += w * x23.x; a3 += w * x23.y;
        }
    }
    // tail: 4 edges per iteration, clamped
    for (; j < e1; j += 4) {
        int jj = j + qw;
        int jc = (jj < e1) ? jj : (e1 - 1);
        int s = csr[jc];
        float av = asrc[s];
        uint2 r = xp2[(long)s * 16 + m];
        float w = (jj < e1) ? lrexp(av + adv) : 0.f;
        d += w;
        float2 x01 = __half22float2(*(__half2*)&r.x);
        float2 x23 = __half22float2(*(__half2*)&r.y);
        a0 += w * x01.x; a1 += w * x01.y;
        a2 += w * x23.x; a3 += w * x23.y;
    }

    // combine the four quarters
    a0 += __shfl_xor(a0, 16); a1 += __shfl_xor(a1, 16);
    a2 += __shfl_xor(a2, 16); a3 += __shfl_xor(a3, 16);
    d  += __shfl_xor(d, 16);
    a0 += __shfl_xor(a0, 32); a1 += __shfl_xor(a1, 32);
    a2 += __shfl_xor(a2, 32); a3 += __shfl_xor(a3, 32);
    d  += __shfl_xor(d, 32);

    if (qw == 0) {
        float inv = 1.0f / d;
        float4 b4 = *(const float4*)&bias[4 * m];
        float4 o;
        o.x = a0 * inv + b4.x;
        o.y = a1 * inv + b4.y;
        o.z = a2 * inv + b4.z;
        o.w = a3 * inv + b4.w;
        *(float4*)&out[(long)v * 64 + 4 * m] = o;
    }
}

// ---------------------------------------------------------------------------
// Launch
// ---------------------------------------------------------------------------
extern "C" void kernel_launch(void* const* d_in, const int* in_sizes, int n_in,
                              void* d_out, int out_size, void* d_ws, size_t ws_size,
                              hipStream_t stream) {
    const float* x_ppi = (const float*)d_in[0];
    const float* x_go  = (const float*)d_in[1];
    const int*   ei    = (const int*)d_in[2];
    const float* W1    = (const float*)d_in[3];
    const float* as1   = (const float*)d_in[4];
    const float* ad1   = (const float*)d_in[5];
    const float* b1    = (const float*)d_in[6];
    const float* W2    = (const float*)d_in[7];
    const float* as2   = (const float*)d_in[8];
    const float* ad2   = (const float*)d_in[9];
    const float* b2    = (const float*)d_in[10];
    float* out = (float*)d_out;

    char* ws = (char*)d_ws;
    size_t off = 0;
    auto alloc = [&](size_t bytes) -> void* {
        void* p = ws + off;
        off = (off + bytes + 255) & ~(size_t)255;
        return p;
    };
    int* deg     = (int*)alloc((size_t)NN * 4);
    int* rs      = (int*)alloc((size_t)(NN + 1) * 4);
    int* cur     = (int*)alloc((size_t)NN * 4);
    int* part    = (int*)alloc(512 * 4);
    int* csr     = (int*)alloc((size_t)ET * 4);
    int* dstv    = (int*)alloc((size_t)ET * 4);
    __half* xp_p = (__half*)alloc((size_t)NN * 128 * 2);   // conv1 p-set features
    __half* xp_g = (__half*)alloc((size_t)NN * 128 * 2);   // conv1 g-set features
    __half* xp2  = (__half*)alloc((size_t)NN * 64 * 2);    // conv2 features fp16
    float* attsp = (float*)alloc((size_t)NN * 4 * 4);
    float* attdp = (float*)alloc((size_t)NN * 4 * 4);
    float* attsg = (float*)alloc((size_t)NN * 4 * 4);
    float* attdg = (float*)alloc((size_t)NN * 4 * 4);
    float* asr2  = (float*)alloc((size_t)NN * 4);
    float* ads2  = (float*)alloc((size_t)NN * 4);
    float* wbp   = (float*)alloc((size_t)ET * 16);         // 4 fp32 weights/edge (p)
    float* wbg   = (float*)alloc((size_t)ET * 16);         // 4 fp32 weights/edge (g)
    __half* hbuf = (__half*)alloc((size_t)NN * 256 * 2);   // conv1 output, fp16
    (void)ws_size; (void)in_sizes; (void)n_in; (void)out_size;

    const int NB = (NN + 255) / 256;        // 391
    const int EB = (ET + 255) / 256;        // 6641
    const int GB = (NN + 127) / 128;        // 782 (MFMA gemm blocks)

    // CSR build (shared by all three convs)
    hipMemsetAsync(deg, 0, (size_t)NN * 4, stream);
    k_count<<<EB, 256, 0, stream>>>(ei, deg);
    k_part<<<NB, 256, 0, stream>>>(deg, part);
    k_scanp<<<1, 512, 0, stream>>>(part, NB);
    k_scan<<<NB, 256, 0, stream>>>(deg, part, rs, cur);
    k_scatter<<<EB, 256, 0, stream>>>(ei, cur, csr, dstv);

    // layer 1: two MFMA GEMMs into separate plain fp16 arrays
    gemm_mfma<128, 128, 1, true><<<GB, 256, 0, stream>>>(x_ppi, W1, xp_p, NN, 0);
    gemm_mfma<128, 128, 1, true><<<GB, 256, 0, stream>>>(x_go, W1, xp_g, NN, 0);
    attn1_plain<<<(NN * 4 + 255) / 256, 256, 0, stream>>>((const __half2*)xp_p, (const __half2*)xp_g,
                                                          as1, ad1, attsp, attdp, attsg, attdg, NN);
    w1prep2<<<EB, 256, 0, stream>>>(csr, dstv, (const float4*)attsp, (const float4*)attdp,
                                    (const float4*)attsg, (const float4*)attdg,
                                    (float4*)wbp, (float4*)wbg);
    // two working-set-split edge passes
    conv1_pass<<<NN / 4, 256, 0, stream>>>(rs, csr, (const uint4*)xp_p, wbp, b1, hbuf, 0);
    conv1_pass<<<NN / 4, 256, 0, stream>>>(rs, csr, (const uint4*)xp_g, wbg, b1, hbuf, 128);

    // layer 2
    gemm_mfma<256, 64, 1, false><<<GB, 256, 0, stream>>>(hbuf, W2, xp2, NN, 0);
    attn2_kernel<<<(NN + 255) / 256, 256, 0, stream>>>((const __half2*)xp2, as2, ad2, asr2, ads2, NN);
    conv2_edge<<<NN / 4, 256, 0, stream>>>(rs, csr, xp2, asr2, ads2, b2, out);
}